// Round 8
// baseline (327.247 us; speedup 1.0000x reference)
//
#include <hip/hip_runtime.h>
#include <stdint.h>

typedef unsigned short u16;
typedef uint8_t u8;
typedef __bf16 bf16x8 __attribute__((ext_vector_type(8)));
typedef float f32x4 __attribute__((ext_vector_type(4)));
typedef long i64x2 __attribute__((ext_vector_type(2)));

#define NTOK 8192
#define DD 512
#define CHK 512
#define CG 2          // chunk-groups (split-K halves for fused attn)
#define CPB 8         // chunks per block (CG*CPB*CHK == NTOK)
#define LOG2E 1.4426950408889634f
#define SCL 0.044194173824159216f          // 1/sqrt(512)
#define SCLL 0.063762069130835270f         // SCL * LOG2E

__device__ __forceinline__ u16 f2bf(float f) {
  union { float f; uint32_t u; } v; v.f = f;
  uint32_t r = v.u + 0x7FFFu + ((v.u >> 16) & 1u);
  return (u16)(r >> 16);
}

// DPP-based 16-lane (row) sum: stays on VALU pipe, avoids LDS-pipe shuffles.
template <int CTRL>
__device__ __forceinline__ float dppadd(float x) {
  int y = __builtin_amdgcn_update_dpp(0, __float_as_int(x), CTRL, 0xF, 0xF, true);
  return x + __int_as_float(y);
}
__device__ __forceinline__ float rowsum16(float x) {
  x = dppadd<0xB1>(x);    // quad_perm(1,0,3,2)
  x = dppadd<0x4E>(x);    // quad_perm(2,3,0,1)
  x = dppadd<0x141>(x);   // row_half_mirror
  x = dppadd<0x140>(x);   // row_mirror
  return x;
}

// async global->LDS, 16B per lane. LDS dest is wave-uniform base + lane*16.
typedef const __attribute__((address_space(1))) unsigned int* gas_t;
typedef __attribute__((address_space(3))) unsigned int* las_t;
__device__ __forceinline__ void gload16(const void* g, void* l) {
  __builtin_amdgcn_global_load_lds((gas_t)g, (las_t)l, 16, 0, 0);
}

// Pipeline fences.
__device__ __forceinline__ void vm4bar() {
  asm volatile("s_waitcnt vmcnt(4)\n\ts_barrier" ::: "memory");
}
__device__ __forceinline__ void vm0bar() {
  asm volatile("s_waitcnt vmcnt(0)\n\ts_barrier" ::: "memory");
}
__device__ __forceinline__ void barx() {
  asm volatile("s_barrier" ::: "memory");
}
// lgkm0 + sched_barrier(0): rule #18 — hipcc hoists register-only MFMA past inline-asm
// lgkmcnt despite the memory clobber; the sched_barrier is the actual fence.
__device__ __forceinline__ void lgkm0() {
  asm volatile("s_waitcnt lgkmcnt(0)" ::: "memory");
  __builtin_amdgcn_sched_barrier(0);
}
// LDS-visibility barrier that does NOT drain vmcnt (unlike __syncthreads): keeps
// prefetched global_load_lds in flight across softmax phase boundaries.
__device__ __forceinline__ void ldsbar() {
  asm volatile("s_waitcnt lgkmcnt(0)\n\ts_barrier" ::: "memory");
}

// k/token interleave within 64-groups: 8-byte group c -> (c&3)*2 + (c>>2).
__device__ __forceinline__ int ilv64(int p) {   // p in 0..63
  const int g = p >> 3;
  return (((g & 3) * 2) + (g >> 2)) * 8 + (p & 7);
}
// composed token permutation for the PV contraction dim (P cols == vT rows)
__device__ __forceinline__ int fperm(int t) {
  const int p = ((t & 15) << 2) | ((t >> 4) & 3);   // permtok within 64
  return (t & ~63) | ilv64(p);
}

// ---------------- prep: cast x->bf16 (+zero lsum), transpose 4 weights, cls q0 ----------------
__global__ void prep_kernel(const float* __restrict__ x, const float* __restrict__ Wq,
                            const float* __restrict__ Wk, const float* __restrict__ Wv,
                            const float* __restrict__ Wo, const float* __restrict__ bq,
                            u16* __restrict__ xb, u16* __restrict__ Wall, u16* __restrict__ WoT,
                            float* __restrict__ lsum, float* __restrict__ q0g) {
  __shared__ float t[32][33];
  const int bid = blockIdx.x;
  const int tid = threadIdx.x;
  if (bid < 4096) {
    int i = bid * 256 + tid;
    if (bid < 32) lsum[bid * 256 + tid] = 0.f;
    float4 v = ((const float4*)x)[i];
    ushort4 o;
    o.x = f2bf(v.x); o.y = f2bf(v.y); o.z = f2bf(v.z); o.w = f2bf(v.w);
    ((ushort4*)xb)[i] = o;
  } else if (bid < 5120) {
    const int tt = bid - 4096;
    const int z = tt >> 8, idx = tt & 255;
    const float* W; u16* WT;
    if (z == 0)      { W = Wq; WT = Wall; }
    else if (z == 1) { W = Wk; WT = Wall + 512 * 512; }
    else if (z == 2) { W = Wv; WT = Wall + 2 * 512 * 512; }
    else             { W = Wo; WT = WoT; }
    const int n0 = (idx & 15) * 32, k0 = (idx >> 4) * 32;
    const int tx = tid & 31, ty = tid >> 5;  // 32 x 8
    #pragma unroll
    for (int i = 0; i < 4; i++)
      t[ty + 8 * i][tx] = W[(k0 + ty + 8 * i) * DD + n0 + tx];
    __syncthreads();
    #pragma unroll
    for (int i = 0; i < 4; i++)
      WT[(n0 + ty + 8 * i) * DD + k0 + tx] = f2bf(t[tx][ty + 8 * i]);
  } else {
    const int c = (bid - 5120) * 256 + tid;
    float acc = bq[c];
    #pragma unroll 8
    for (int i = 0; i < 512; i++) acc += x[i] * Wq[i * 512 + c];
    q0g[c] = acc;
  }
}

// ---------------- fused q/k/v projection: 256 thr, 128x128 tiles, counted-vmcnt dbuf ----------------
__launch_bounds__(256, 3)
__global__ void qkv_kernel(const u16* __restrict__ A, const u16* __restrict__ Wall,
                           const float* __restrict__ bq, const float* __restrict__ bk,
                           const float* __restrict__ bv, u8* __restrict__ qb8,
                           u8* __restrict__ kb8, u8* __restrict__ vT8) {
  __shared__ __align__(16) u16 As[2][128 * 32];
  __shared__ __align__(16) u16 Bs[2][128 * 32];
  const int m0 = blockIdx.x * 128;
  const int n0g = blockIdx.y * 128;
  const int which = blockIdx.y >> 2;
  const int n0 = n0g & 511;
  const int tid = threadIdx.x;
  const int w = tid >> 6, lane = tid & 63, lm = lane & 15, quad = lane >> 4;
  const int wm = w & 1, wn = w >> 1;
  f32x4 acc[4][4] = {};
  const int soff = tid * 16;
  const int srow = soff >> 6;
  const int scol = soff & 63;
  const char* Ag = (const char*)A + ((size_t)(m0 + srow) * DD) * 2 + scol;
  const char* Bg = (const char*)Wall + ((size_t)(n0g + srow) * DD) * 2 + scol;
  char* Al = (char*)As + w * 1024;
  char* Bl = (char*)Bs + w * 1024;
  const size_t rs = (size_t)64 * DD * 2;

  auto stage = [&](int kk, int buf) {
    const char* ag = Ag + (size_t)kk * 2;
    const char* bg = Bg + (size_t)kk * 2;
    char* al = Al + buf * 8192;
    char* bl = Bl + buf * 8192;
    gload16(ag, al);
    gload16(ag + rs, al + 4096);
    gload16(bg, bl);
    gload16(bg + rs, bl + 4096);
  };

  stage(0, 0);
  for (int t = 0; t < 16; ++t) {
    const int cur = t & 1;
    if (t < 15) { stage((t + 1) * 32, cur ^ 1); vm4bar(); }
    else vm0bar();
    bf16x8 af[4], bfr[4];
    #pragma unroll
    for (int i = 0; i < 4; i++) af[i] = *(const bf16x8*)&As[cur][(wm * 64 + i * 16 + lm) * 32 + quad * 8];
    #pragma unroll
    for (int j = 0; j < 4; j++) bfr[j] = *(const bf16x8*)&Bs[cur][(wn * 64 + j * 16 + lm) * 32 + quad * 8];
    lgkm0();
    #pragma unroll
    for (int i = 0; i < 4; i++)
      #pragma unroll
      for (int j = 0; j < 4; j++)
        acc[i][j] = __builtin_amdgcn_mfma_f32_16x16x32_bf16(af[i], bfr[j], acc[i][j], 0, 0, 0);
    barx();
  }
  const float* bias = (which == 0) ? bq : (which == 1) ? bk : bv;
  #pragma unroll
  for (int i = 0; i < 4; i++) {
    const int row0 = m0 + wm * 64 + i * 16 + quad * 4;
    #pragma unroll
    for (int j = 0; j < 4; j++) {
      const int col = n0 + wn * 64 + j * 16 + lm;
      const float bv_ = bias[col];
      if (which == 2) {
        #pragma unroll
        for (int r = 0; r < 4; r++) {
          const float val = acc[i][j][r] + bv_;
          uint32_t pk = __builtin_amdgcn_cvt_pk_fp8_f32(val, val, 0, false);
          vT8[(size_t)col * NTOK + fperm(row0 + r)] = (u8)(pk & 0xFF);
        }
      } else {
        u8* dst = (which == 0) ? qb8 : kb8;
        const int icol = (col & ~63) | ilv64(col & 63);   // k-interleave
        #pragma unroll
        for (int r = 0; r < 4; r++) {
          const float val = acc[i][j][r] + bv_;
          uint32_t pk = __builtin_amdgcn_cvt_pk_fp8_f32(val, val, 0, false);
          dst[(size_t)(row0 + r) * DD + icol] = (u8)(pk & 0xFF);
        }
      }
    }
  }
}

// ---------------- out projection: 256 thr, 128x128 tiles, counted-vmcnt dbuf ----------------
__launch_bounds__(256, 3)
__global__ void outproj_kernel(const u16* __restrict__ A, const u16* __restrict__ BT,
                               const float* __restrict__ bias, float* __restrict__ outp,
                               const float* __restrict__ resid) {
  __shared__ __align__(16) u16 As[2][128 * 32];
  __shared__ __align__(16) u16 Bs[2][128 * 32];
  const int m0 = blockIdx.x * 128, n0 = blockIdx.y * 128;
  const int tid = threadIdx.x;
  const int w = tid >> 6, lane = tid & 63, lm = lane & 15, quad = lane >> 4;
  const int wm = w & 1, wn = w >> 1;
  f32x4 acc[4][4] = {};
  const int soff = tid * 16;
  const int srow = soff >> 6;
  const int scol = soff & 63;
  const char* Ag = (const char*)A + ((size_t)(m0 + srow) * DD) * 2 + scol;
  const char* Bg = (const char*)BT + ((size_t)(n0 + srow) * DD) * 2 + scol;
  char* Al = (char*)As + w * 1024;
  char* Bl = (char*)Bs + w * 1024;
  const size_t rs = (size_t)64 * DD * 2;

  auto stage = [&](int kk, int buf) {
    const char* ag = Ag + (size_t)kk * 2;
    const char* bg = Bg + (size_t)kk * 2;
    char* al = Al + buf * 8192;
    char* bl = Bl + buf * 8192;
    gload16(ag, al);
    gload16(ag + rs, al + 4096);
    gload16(bg, bl);
    gload16(bg + rs, bl + 4096);
  };

  stage(0, 0);
  for (int t = 0; t < 16; ++t) {
    const int cur = t & 1;
    if (t < 15) { stage((t + 1) * 32, cur ^ 1); vm4bar(); }
    else vm0bar();
    bf16x8 af[4], bfr[4];
    #pragma unroll
    for (int i = 0; i < 4; i++) af[i] = *(const bf16x8*)&As[cur][(wm * 64 + i * 16 + lm) * 32 + quad * 8];
    #pragma unroll
    for (int j = 0; j < 4; j++) bfr[j] = *(const bf16x8*)&Bs[cur][(wn * 64 + j * 16 + lm) * 32 + quad * 8];
    lgkm0();
    #pragma unroll
    for (int i = 0; i < 4; i++)
      #pragma unroll
      for (int j = 0; j < 4; j++)
        acc[i][j] = __builtin_amdgcn_mfma_f32_16x16x32_bf16(af[i], bfr[j], acc[i][j], 0, 0, 0);
    barx();
  }
  #pragma unroll
  for (int i = 0; i < 4; i++) {
    const int row0 = m0 + wm * 64 + i * 16 + quad * 4;
    #pragma unroll
    for (int j = 0; j < 4; j++) {
      const int col = n0 + wn * 64 + j * 16 + lm;
      const float bv = bias[col];
      #pragma unroll
      for (int r = 0; r < 4; r++) {
        const size_t idx = (size_t)(row0 + r) * DD + col;
        outp[idx] = acc[i][j][r] + bv + resid[idx];
      }
    }
  }
}

// ---------------- fused attention (R8): QK^T + chunk-softmax + PV in one kernel ----------------
// Block = 64 q-rows x 4096 keys (8 chunks). Grid (128, 2) = 256 blocks = 1/CU exactly.
// Q persistent in LDS (32 KB). Per chunk: stream K (8 x 64-D substeps, dbuf) -> S in regs;
// softmax phases A/B/C (as scores) with P written to LDS (fperm byte layout, +16B row pad);
// stream V (8 x 64-token substeps, same dbuf) -> O accumulated in regs across chunks.
// V(0) prefetch issued at QK^T's last substep; softmax uses ldsbar (lgkm-only drain) so the
// in-flight V loads survive the phase boundaries. Partial O (fp32) + lsum atomicAdd out.
// Eliminates: P8 (64 MB HBM write + rereads), half of `part`, one kernel launch.
__launch_bounds__(512, 2)
__global__ void fused_attn_kernel(const u8* __restrict__ qb8, const u8* __restrict__ kb8,
                                  const u8* __restrict__ vT8, float* __restrict__ part,
                                  float* __restrict__ lsum) {
  __shared__ __align__(16) u8 Qs[8 * 64 * 64];    // 32 KB: 8 D-subtiles (64 rows x 64 B)
  __shared__ __align__(16) u8 Bs[2][512 * 64];    // 64 KB: K/V staging dbuf (time-shared)
  __shared__ __align__(16) u8 Pl[64][528];        // 33 KB: P tile, fperm layout, +16B row pad
  __shared__ float hS[8][64], hP[8][64], hZ[64];
  const int m0 = blockIdx.x * 64;
  const int cg = blockIdx.y;                      // 0..1 (key half)
  const int tid = threadIdx.x;
  const int w = tid >> 6, lane = tid & 63, lm = lane & 15, quad = lane >> 4;
  const int wsl = w;                              // wave slice: keys (QK^T) / D-cols (PV)
  f32x4 acc[4][4] = {};                           // O: rows i*16+quad*4+r, cols wsl*64+j*16+lm
  const int srA = tid >> 2;                                   // 0..127
  const int scS = ((tid & 3) ^ ((srA >> 1) & 3)) * 16;        // staging swizzle
  const u8* Qg = qb8 + (size_t)(m0 + (srA & 63)) * DD + scS;  // used by tid<256 only
  const u8* Kg = kb8 + ((size_t)cg * CPB * CHK + srA) * DD + scS;
  const u8* Vg = vT8 + (size_t)srA * NTOK + (size_t)cg * CPB * CHK + scS;
  u8* Bl = (u8*)Bs + w * 1024;
  const int csel = ((quad ^ ((lm >> 1) & 3)) * 16);

  auto stageK = [&](int c, int kk, int buf) {     // K subtile: 512 keys x 64 D = 32 KB
    u8* bl = Bl + buf * 32768;
    const u8* kg = Kg + (size_t)c * CHK * DD + kk * 64;
    gload16(kg, bl);
    gload16(kg + (size_t)128 * DD, bl + 8192);
    gload16(kg + (size_t)256 * DD, bl + 16384);
    gload16(kg + (size_t)384 * DD, bl + 24576);
  };
  auto stageV = [&](int c, int ks, int buf) {     // V subtile: 512 D x 64 tokens = 32 KB
    u8* bl = Bl + buf * 32768;
    const u8* vg = Vg + c * CHK + ks * 64;
    gload16(vg, bl);
    gload16(vg + (size_t)128 * NTOK, bl + 8192);
    gload16(vg + (size_t)256 * NTOK, bl + 16384);
    gload16(vg + (size_t)384 * NTOK, bl + 24576);
  };

  // persistent Q: 8 subtiles, waves 0-3 (drained by first vm0bar)
  if (tid < 256) {
    #pragma unroll
    for (int kd = 0; kd < 8; kd++)
      gload16(Qg + kd * 64, Qs + kd * 4096 + w * 1024);
  }

  float lrow = 0.f;                               // per-thread (tid<64) l accumulator
  const int newc = ((lm >> 1) & 3) * 2 + (lm >> 3);
  const int pbyte = wsl * 64 + newc * 8 + (lm & 1) * 4;

  for (int c = 0; c < CPB; ++c) {
    // ---- QK^T: S = Q @ K_c^T over 8 D-substeps ----
    f32x4 s[4][4] = {};
    stageK(c, 0, 0);
    vm0bar();
    #pragma unroll
    for (int t = 0; t < 8; ++t) {
      const int cur = t & 1;
      if (t < 7) stageK(c, t + 1, cur ^ 1);
      else stageV(c, 0, 0);                       // V(0) prefetch: buf0 free (last read t=6, barrier'd)
      i64x2 afv[4], bfv[4];
      #pragma unroll
      for (int i = 0; i < 4; i++)
        afv[i] = *(const i64x2*)&Qs[t * 4096 + (i * 16 + lm) * 64 + csel];
      #pragma unroll
      for (int j = 0; j < 4; j++)
        bfv[j] = *(const i64x2*)&Bs[cur][(wsl * 64 + j * 16 + lm) * 64 + csel];
      lgkm0();
      __builtin_amdgcn_s_setprio(1);
      #pragma unroll
      for (int i = 0; i < 4; i++)
        #pragma unroll
        for (int j = 0; j < 4; j++) {
          s[i][j] = __builtin_amdgcn_mfma_f32_16x16x32_fp8_fp8(afv[i].x, bfv[j].x, s[i][j], 0, 0, 0);
          s[i][j] = __builtin_amdgcn_mfma_f32_16x16x32_fp8_fp8(afv[i].y, bfv[j].y, s[i][j], 0, 0, 0);
        }
      __builtin_amdgcn_s_setprio(0);
      if (t < 7) vm0bar();                        // next K landed while MFMAs ran
    }
    // ---- softmax phase A: e = exp2(s*SCLL); per-wave 64-key partial row sums ----
    // (V(0) loads remain in flight: ldsbar drains lgkm only, not vmcnt)
    #pragma unroll
    for (int i = 0; i < 4; i++) {
      #pragma unroll
      for (int reg = 0; reg < 4; reg++) {
        float z = 0.f;
        #pragma unroll
        for (int j = 0; j < 4; j++) {
          float e = exp2f(s[i][j][reg] * SCLL);
          s[i][j][reg] = e;
          z += e;
        }
        z = rowsum16(z);
        if (lm == 0) hS[wsl][i * 16 + quad * 4 + reg] = z;
      }
    }
    ldsbar();
    // ---- phase B: row totals -> hZ = LOG2E / Z ----
    if (tid < 64) {
      float t = 0.f;
      #pragma unroll
      for (int w2 = 0; w2 < 8; w2++) t += hS[w2][tid];
      hZ[tid] = LOG2E / t;
    }
    ldsbar();
    // ---- phase C: p = exp2(e * LOG2E/Z) -> Pl (LDS) + partial l ----
    #pragma unroll
    for (int i = 0; i < 4; i++) {
      #pragma unroll
      for (int reg = 0; reg < 4; reg++) {
        const int rl = i * 16 + quad * 4 + reg;
        const float iz = hZ[rl];
        const float p0 = exp2f(s[i][0][reg] * iz);
        const float p1 = exp2f(s[i][1][reg] * iz);
        const float p2 = exp2f(s[i][2][reg] * iz);
        const float p3 = exp2f(s[i][3][reg] * iz);
        float zp = (p0 + p1) + (p2 + p3);
        zp = rowsum16(zp);
        if (lm == 0) hP[wsl][rl] = zp;
        uint32_t o = __builtin_amdgcn_cvt_pk_fp8_f32(p0, p1, 0, false);
        o = __builtin_amdgcn_cvt_pk_fp8_f32(p2, p3, o, true);
        *(uint32_t*)&Pl[rl][pbyte] = o;
      }
    }
    ldsbar();
    if (tid < 64) {
      float t = 0.f;
      #pragma unroll
      for (int w2 = 0; w2 < 8; w2++) t += hP[w2][tid];
      lrow += t;
    }
    vm0bar();                                     // V(0) landed + barrier
    // ---- PV: O += P @ V_c over 8 token-substeps ----
    #pragma unroll
    for (int t = 0; t < 8; ++t) {
      const int cur = t & 1;
      if (t < 7) stageV(c, t + 1, cur ^ 1);
      i64x2 afv[4], bfv[4];
      #pragma unroll
      for (int i = 0; i < 4; i++)
        afv[i] = *(const i64x2*)&Pl[i * 16 + lm][t * 64 + quad * 16];
      #pragma unroll
      for (int j = 0; j < 4; j++)
        bfv[j] = *(const i64x2*)&Bs[cur][(wsl * 64 + j * 16 + lm) * 64 + csel];
      lgkm0();
      __builtin_amdgcn_s_setprio(1);
      #pragma unroll
      for (int i = 0; i < 4; i++)
        #pragma unroll
        for (int j = 0; j < 4; j++) {
          acc[i][j] = __builtin_amdgcn_mfma_f32_16x16x32_fp8_fp8(afv[i].x, bfv[j].x, acc[i][j], 0, 0, 0);
          acc[i][j] = __builtin_amdgcn_mfma_f32_16x16x32_fp8_fp8(afv[i].y, bfv[j].y, acc[i][j], 0, 0, 0);
        }
      __builtin_amdgcn_s_setprio(0);
      if (t < 7) vm0bar();
      else barx();                                // chunk boundary: Pl/Bs reuse fenced by lgkm0s
    }
  }
  // ---- epilogue: partial O (fp32) + lsum ----
  if (tid < 64) atomicAdd(&lsum[m0 + tid], lrow);
  float* po = part + (size_t)cg * NTOK * DD;
  #pragma unroll
  for (int i = 0; i < 4; i++) {
    const int row0 = m0 + i * 16 + quad * 4;
    #pragma unroll
    for (int j = 0; j < 4; j++) {
      const int col = wsl * 64 + j * 16 + lm;
      #pragma unroll
      for (int r = 0; r < 4; r++)
        po[(size_t)(row0 + r) * DD + col] = acc[i][j][r];
    }
  }
}

// ---------------- PV reduce (2 parts): attnb = (p0 + p1) / lsum ----------------
__global__ void pv_reduce_kernel(const float* __restrict__ part, const float* __restrict__ lsum,
                                 u16* __restrict__ attnb) {
  const int idx = blockIdx.x * 256 + threadIdx.x;
  const int row = idx >> 7;
  const int c4 = (idx & 127) << 2;
  const float* p = part + (size_t)row * DD + c4;
  const size_t stride = (size_t)NTOK * DD;
  float4 a = *(const float4*)(p);
  float4 b = *(const float4*)(p + stride);
  const float inv = 1.0f / lsum[row];
  ushort4 o;
  o.x = f2bf((a.x + b.x) * inv);
  o.y = f2bf((a.y + b.y) * inv);
  o.z = f2bf((a.z + b.z) * inv);
  o.w = f2bf((a.w + b.w) * inv);
  *(ushort4*)(attnb + (size_t)row * DD + c4) = o;
}

// ---------------- cls row (exact fp32) ----------------
__global__ void cls_u_kernel(const float* __restrict__ Wk, const float* __restrict__ bk,
                             const float* __restrict__ q0g, float* __restrict__ uc) {
  __shared__ float q0[512];
  const int tid = threadIdx.x;
  q0[tid] = q0g[tid];
  q0[tid + 256] = q0g[tid + 256];
  __syncthreads();
  if (blockIdx.x < 8) {
    const int c = blockIdx.x * 64 + (tid >> 2), ii = tid & 3;
    float acc = 0.f;
    #pragma unroll 8
    for (int j = ii; j < 512; j += 4) acc += Wk[(size_t)c * 512 + j] * q0[j];
    acc += __shfl_xor(acc, 1, 64);
    acc += __shfl_xor(acc, 2, 64);
    if (ii == 0) uc[c] = acc;
  } else if (tid < 64) {
    float acc = 0.f;
    #pragma unroll 8
    for (int j = tid; j < 512; j += 64) acc += bk[j] * q0[j];
    #pragma unroll
    for (int off = 1; off < 64; off <<= 1) acc += __shfl_xor(acc, off, 64);
    if (tid == 0) uc[512] = acc;
  }
}

__global__ void cls_scores_kernel(const float* __restrict__ x, const float* __restrict__ uc,
                                  float* __restrict__ s0) {
  __shared__ float u[512];
  __shared__ float c0s;
  int tid = threadIdx.x;  // 256
  for (int i = tid; i < 512; i += 256) u[i] = uc[i];
  if (tid == 0) c0s = uc[512];
  __syncthreads();
  int rowg = blockIdx.x * 32 + (tid >> 3);
  int ii = tid & 7;
  const float* xr = x + rowg * 512;
  float acc = 0.f;
  for (int i = ii; i < 512; i += 8) acc += xr[i] * u[i];
  acc += __shfl_xor(acc, 1, 64);
  acc += __shfl_xor(acc, 2, 64);
  acc += __shfl_xor(acc, 4, 64);
  if (ii == 0) s0[rowg] = (acc + c0s) * SCL;
}

__global__ void cls_softmax_kernel(const float* __restrict__ s0, float* __restrict__ out) {
  int tid = threadIdx.x;  // 1024 = 16 waves, wave w = chunk w
  int w = tid >> 6, lane = tid & 63;
  const float* sc = s0 + w * 512;
  float v[8];
  float m = -1e30f;
  #pragma unroll
  for (int j = 0; j < 8; j++) { v[j] = sc[lane * 8 + j]; m = fmaxf(m, v[j]); }
  for (int off = 1; off < 64; off <<= 1) m = fmaxf(m, __shfl_xor(m, off, 64));
  float z = 0.f;
  #pragma unroll
  for (int j = 0; j < 8; j++) { v[j] = expf(v[j] - m); z += v[j]; }
  for (int off = 1; off < 64; off <<= 1) z += __shfl_xor(z, off, 64);
  float invz = 1.f / z;
  float l = 0.f;
  #pragma unroll
  for (int j = 0; j < 8; j++) { v[j] = expf(v[j] * invz); l += v[j]; }
  for (int off = 1; off < 64; off <<= 1) l += __shfl_xor(l, off, 64);
  __shared__ float lw[16];
  if (lane == 0) lw[w] = l;
  __syncthreads();
  float L = 0.f;
  for (int i = 0; i < 16; i++) L += lw[i];
  float invL = 1.f / L;
  #pragma unroll
  for (int j = 0; j < 8; j++) out[w * 512 + lane * 8 + j] = v[j] * invL;
}

extern "C" void kernel_launch(void* const* d_in, const int* in_sizes, int n_in,
                              void* d_out, int out_size, void* d_ws, size_t ws_size,
                              hipStream_t stream) {
  const float* x  = (const float*)d_in[0];
  const float* Wq = (const float*)d_in[1];
  const float* bq = (const float*)d_in[2];
  const float* Wk = (const float*)d_in[3];
  const float* bk = (const float*)d_in[4];
  const float* Wv = (const float*)d_in[5];
  const float* bv = (const float*)d_in[6];
  const float* Wo = (const float*)d_in[7];
  const float* bo = (const float*)d_in[8];
  float* out = (float*)d_out;

  char* ws = (char*)d_ws;
  u16* xb    = (u16*)(ws);                  // 8 MB
  u16* Wall  = (u16*)(ws + 8388608);        // 1.5 MB
  u16* WoT   = (u16*)(ws + 9961472);        // 512 KB
  u8*  qb8   = (u8*)(ws + 10485760);        // 4 MB fp8 (k-interleaved)
  u8*  kb8   = (u8*)(ws + 14680064);        // 4 MB fp8 (k-interleaved)
  u8*  vT8   = (u8*)(ws + 18874368);        // 4 MB fp8 (fperm tokens)
  u16* attnb = (u16*)(ws + 23068672);       // 8 MB
  float* q0g = (float*)(ws + 31457280);     // 512 f
  float* uc  = (float*)(ws + 31461376);     // 513 f
  float* s0  = (float*)(ws + 31465472);     // 8192 f
  float* lsum= (float*)(ws + 31498240);     // 8192 f
  float* part= (float*)(ws + 98639872);     // 2 x 16 MB fp32 partial O

  prep_kernel<<<5122, 256, 0, stream>>>(x, Wq, Wk, Wv, Wo, bq, xb, Wall, WoT, lsum, q0g);

  qkv_kernel<<<dim3(NTOK / 128, 12), 256, 0, stream>>>(xb, Wall, bq, bk, bv, qb8, kb8, vT8);

  fused_attn_kernel<<<dim3(NTOK / 64, CG), 512, 0, stream>>>(qb8, kb8, vT8, part, lsum);

  pv_reduce_kernel<<<NTOK * DD / 4 / 256, 256, 0, stream>>>(part, lsum, attnb);

  outproj_kernel<<<dim3(NTOK / 128, DD / 128), 256, 0, stream>>>(attnb, WoT, bo, out, x);

  cls_u_kernel<<<9, 256, 0, stream>>>(Wk, bk, q0g, uc);
  cls_scores_kernel<<<NTOK / 32, 256, 0, stream>>>(x, uc, s0);
  cls_softmax_kernel<<<1, 1024, 0, stream>>>(s0, out + (size_t)NTOK * DD);
}

// Round 9
// 299.261 us; speedup vs baseline: 1.0935x; 1.0935x over previous
//
#include <hip/hip_runtime.h>
#include <stdint.h>

typedef unsigned short u16;
typedef uint8_t u8;
typedef __bf16 bf16x8 __attribute__((ext_vector_type(8)));
typedef float f32x4 __attribute__((ext_vector_type(4)));
typedef long i64x2 __attribute__((ext_vector_type(2)));

#define NTOK 8192
#define DD 512
#define CHK 512
#define NCH 16
#define KSPLIT 4
#define KLEN 2048
#define LOG2E 1.4426950408889634f
#define SCL 0.044194173824159216f          // 1/sqrt(512)
#define SCLL 0.063762069130835270f         // SCL * LOG2E

__device__ __forceinline__ u16 f2bf(float f) {
  union { float f; uint32_t u; } v; v.f = f;
  uint32_t r = v.u + 0x7FFFu + ((v.u >> 16) & 1u);
  return (u16)(r >> 16);
}

// DPP-based 16-lane (row) sum: stays on VALU pipe, avoids LDS-pipe shuffles.
template <int CTRL>
__device__ __forceinline__ float dppadd(float x) {
  int y = __builtin_amdgcn_update_dpp(0, __float_as_int(x), CTRL, 0xF, 0xF, true);
  return x + __int_as_float(y);
}
__device__ __forceinline__ float rowsum16(float x) {
  x = dppadd<0xB1>(x);    // quad_perm(1,0,3,2)
  x = dppadd<0x4E>(x);    // quad_perm(2,3,0,1)
  x = dppadd<0x141>(x);   // row_half_mirror
  x = dppadd<0x140>(x);   // row_mirror
  return x;
}

// async global->LDS, 16B per lane. LDS dest is wave-uniform base + lane*16.
typedef const __attribute__((address_space(1))) unsigned int* gas_t;
typedef __attribute__((address_space(3))) unsigned int* las_t;
__device__ __forceinline__ void gload16(const void* g, void* l) {
  __builtin_amdgcn_global_load_lds((gas_t)g, (las_t)l, 16, 0, 0);
}

// Pipeline fences.
// vm4bar (counted): kernels where EVERY wave issues exactly 4 loads/stage —
// measured win on qkv/outproj/gemm (uniform counts); measured LOSS on scores
// (Q-waves issue 5 -> over-wait on a fresh load).
__device__ __forceinline__ void vm4bar() {
  asm volatile("s_waitcnt vmcnt(4)\n\ts_barrier" ::: "memory");
}
// vm0bar: drain own loads + barrier (R2/R5 scores arrangement: rotated
// single-barrier pipeline — issue->wait window = one full compute phase).
__device__ __forceinline__ void vm0bar() {
  asm volatile("s_waitcnt vmcnt(0)\n\ts_barrier" ::: "memory");
}
__device__ __forceinline__ void barx() {
  asm volatile("s_barrier" ::: "memory");
}
// lgkm0 + sched_barrier(0): rule #18 — hipcc hoists register-only MFMA past inline-asm
// lgkmcnt despite the memory clobber; the sched_barrier is the actual fence.
__device__ __forceinline__ void lgkm0() {
  asm volatile("s_waitcnt lgkmcnt(0)" ::: "memory");
  __builtin_amdgcn_sched_barrier(0);
}

// k/token interleave within 64-groups: 8-byte group c -> (c&3)*2 + (c>>2).
// Makes a lane's two K=32 MFMA fragments (k=q*8.., k=32+q*8..) contiguous 16B.
__device__ __forceinline__ int ilv64(int p) {   // p in 0..63
  const int g = p >> 3;
  return (((g & 3) * 2) + (g >> 2)) * 8 + (p & 7);
}

// ---------------- prep: cast x->bf16 (+zero lsum), transpose 4 weights, cls q0 ----------------
__global__ void prep_kernel(const float* __restrict__ x, const float* __restrict__ Wq,
                            const float* __restrict__ Wk, const float* __restrict__ Wv,
                            const float* __restrict__ Wo, const float* __restrict__ bq,
                            u16* __restrict__ xb, u16* __restrict__ Wall, u16* __restrict__ WoT,
                            float* __restrict__ lsum, float* __restrict__ q0g) {
  __shared__ float t[32][33];
  const int bid = blockIdx.x;
  const int tid = threadIdx.x;
  if (bid < 4096) {
    int i = bid * 256 + tid;
    if (bid < 32) lsum[bid * 256 + tid] = 0.f;
    float4 v = ((const float4*)x)[i];
    ushort4 o;
    o.x = f2bf(v.x); o.y = f2bf(v.y); o.z = f2bf(v.z); o.w = f2bf(v.w);
    ((ushort4*)xb)[i] = o;
  } else if (bid < 5120) {
    const int tt = bid - 4096;
    const int z = tt >> 8, idx = tt & 255;
    const float* W; u16* WT;
    if (z == 0)      { W = Wq; WT = Wall; }
    else if (z == 1) { W = Wk; WT = Wall + 512 * 512; }
    else if (z == 2) { W = Wv; WT = Wall + 2 * 512 * 512; }
    else             { W = Wo; WT = WoT; }
    const int n0 = (idx & 15) * 32, k0 = (idx >> 4) * 32;
    const int tx = tid & 31, ty = tid >> 5;  // 32 x 8
    #pragma unroll
    for (int i = 0; i < 4; i++)
      t[ty + 8 * i][tx] = W[(k0 + ty + 8 * i) * DD + n0 + tx];
    __syncthreads();
    #pragma unroll
    for (int i = 0; i < 4; i++)
      WT[(n0 + ty + 8 * i) * DD + k0 + tx] = f2bf(t[tx][ty + 8 * i]);
  } else {
    const int c = (bid - 5120) * 256 + tid;
    float acc = bq[c];
    #pragma unroll 8
    for (int i = 0; i < 512; i++) acc += x[i] * Wq[i * 512 + c];
    q0g[c] = acc;
  }
}

// ---------------- fused q/k/v projection: 256 thr, 128x128 tiles, counted-vmcnt dbuf ----------------
// by: 0..11; which = by>>2 (0=q fp8 k-interleaved, 1=k fp8 k-interleaved, 2=v fp8 T+fperm)
// R9: epilogue stages the permuted fp8 tile in LDS (16 KB, reuses As) then writes
// global as 4x dwordx4/thread. ilv64/fperm are bijections within 64-token groups, so
// each output row (q/k) / col (v) of the 128x128 tile is a contiguous 128B run.
// Replaces 64 scattered 1-byte global stores per thread (4.2M byte-stores/launch).
__launch_bounds__(256, 3)
__global__ void qkv_kernel(const u16* __restrict__ A, const u16* __restrict__ Wall,
                           const float* __restrict__ bq, const float* __restrict__ bk,
                           const float* __restrict__ bv, u8* __restrict__ qb8,
                           u8* __restrict__ kb8, u8* __restrict__ vT8) {
  __shared__ __align__(16) u16 As[2][128 * 32];
  __shared__ __align__(16) u16 Bs[2][128 * 32];
  const int m0 = blockIdx.x * 128;
  const int n0g = blockIdx.y * 128;
  const int which = blockIdx.y >> 2;
  const int n0 = n0g & 511;
  const int tid = threadIdx.x;
  const int w = tid >> 6, lane = tid & 63, lm = lane & 15, quad = lane >> 4;
  const int wm = w & 1, wn = w >> 1;
  f32x4 acc[4][4] = {};
  const int soff = tid * 16;
  const int srow = soff >> 6;
  const int scol = soff & 63;
  const char* Ag = (const char*)A + ((size_t)(m0 + srow) * DD) * 2 + scol;
  const char* Bg = (const char*)Wall + ((size_t)(n0g + srow) * DD) * 2 + scol;
  char* Al = (char*)As + w * 1024;
  char* Bl = (char*)Bs + w * 1024;
  const size_t rs = (size_t)64 * DD * 2;

  auto stage = [&](int kk, int buf) {
    const char* ag = Ag + (size_t)kk * 2;
    const char* bg = Bg + (size_t)kk * 2;
    char* al = Al + buf * 8192;
    char* bl = Bl + buf * 8192;
    gload16(ag, al);
    gload16(ag + rs, al + 4096);
    gload16(bg, bl);
    gload16(bg + rs, bl + 4096);
  };

  stage(0, 0);
  for (int t = 0; t < 16; ++t) {
    const int cur = t & 1;
    if (t < 15) { stage((t + 1) * 32, cur ^ 1); vm4bar(); }
    else vm0bar();
    bf16x8 af[4], bfr[4];
    #pragma unroll
    for (int i = 0; i < 4; i++) af[i] = *(const bf16x8*)&As[cur][(wm * 64 + i * 16 + lm) * 32 + quad * 8];
    #pragma unroll
    for (int j = 0; j < 4; j++) bfr[j] = *(const bf16x8*)&Bs[cur][(wn * 64 + j * 16 + lm) * 32 + quad * 8];
    lgkm0();
    #pragma unroll
    for (int i = 0; i < 4; i++)
      #pragma unroll
      for (int j = 0; j < 4; j++)
        acc[i][j] = __builtin_amdgcn_mfma_f32_16x16x32_bf16(af[i], bfr[j], acc[i][j], 0, 0, 0);
    barx();
  }
  // ---- epilogue: LDS-staged permuted tile -> coalesced 16B global stores ----
  // safe to reuse As: every wave drained its ds_reads (lgkm0) before the final barx.
  const float* bias = (which == 0) ? bq : (which == 1) ? bk : bv;
  u8* tile = (u8*)As;   // 16 KB = 128 x 128 bytes
  #pragma unroll
  for (int i = 0; i < 4; i++) {
    const int rl0 = wm * 64 + i * 16 + quad * 4;
    #pragma unroll
    for (int j = 0; j < 4; j++) {
      const int cl = wn * 64 + j * 16 + lm;
      const float bv_ = bias[n0 + cl];
      if (which == 2) {
        // tile[col][fperm-local(token)]
        #pragma unroll
        for (int r = 0; r < 4; r++) {
          const float val = acc[i][j][r] + bv_;
          uint32_t pk = __builtin_amdgcn_cvt_pk_fp8_f32(val, val, 0, false);
          const int rl = rl0 + r;
          const int tl = (rl & 64) | ilv64(((rl & 15) << 2) | ((rl >> 4) & 3));
          tile[cl * 128 + tl] = (u8)(pk & 0xFF);
        }
      } else {
        // tile[row][ilv64-local(col)]
        const int icl = (cl & 64) | ilv64(cl & 63);
        #pragma unroll
        for (int r = 0; r < 4; r++) {
          const float val = acc[i][j][r] + bv_;
          uint32_t pk = __builtin_amdgcn_cvt_pk_fp8_f32(val, val, 0, false);
          tile[(rl0 + r) * 128 + icl] = (u8)(pk & 0xFF);
        }
      }
    }
  }
  __syncthreads();
  const int lrow = tid >> 1, half = tid & 1;
  const uint4* s4 = (const uint4*)(tile + lrow * 128 + half * 64);
  if (which == 2) {
    uint4* p = (uint4*)(vT8 + (size_t)(n0 + lrow) * NTOK + m0 + half * 64);
    #pragma unroll
    for (int k = 0; k < 4; k++) p[k] = s4[k];
  } else {
    u8* dst = (which == 0) ? qb8 : kb8;
    uint4* p = (uint4*)(dst + (size_t)(m0 + lrow) * DD + n0 + half * 64);
    #pragma unroll
    for (int k = 0; k < 4; k++) p[k] = s4[k];
  }
}

// ---------------- out projection: 256 thr, 128x128 tiles, counted-vmcnt dbuf ----------------
__launch_bounds__(256, 3)
__global__ void outproj_kernel(const u16* __restrict__ A, const u16* __restrict__ BT,
                               const float* __restrict__ bias, float* __restrict__ outp,
                               const float* __restrict__ resid) {
  __shared__ __align__(16) u16 As[2][128 * 32];
  __shared__ __align__(16) u16 Bs[2][128 * 32];
  const int m0 = blockIdx.x * 128, n0 = blockIdx.y * 128;
  const int tid = threadIdx.x;
  const int w = tid >> 6, lane = tid & 63, lm = lane & 15, quad = lane >> 4;
  const int wm = w & 1, wn = w >> 1;
  f32x4 acc[4][4] = {};
  const int soff = tid * 16;
  const int srow = soff >> 6;
  const int scol = soff & 63;
  const char* Ag = (const char*)A + ((size_t)(m0 + srow) * DD) * 2 + scol;
  const char* Bg = (const char*)BT + ((size_t)(n0 + srow) * DD) * 2 + scol;
  char* Al = (char*)As + w * 1024;
  char* Bl = (char*)Bs + w * 1024;
  const size_t rs = (size_t)64 * DD * 2;

  auto stage = [&](int kk, int buf) {
    const char* ag = Ag + (size_t)kk * 2;
    const char* bg = Bg + (size_t)kk * 2;
    char* al = Al + buf * 8192;
    char* bl = Bl + buf * 8192;
    gload16(ag, al);
    gload16(ag + rs, al + 4096);
    gload16(bg, bl);
    gload16(bg + rs, bl + 4096);
  };

  stage(0, 0);
  for (int t = 0; t < 16; ++t) {
    const int cur = t & 1;
    if (t < 15) { stage((t + 1) * 32, cur ^ 1); vm4bar(); }
    else vm0bar();
    bf16x8 af[4], bfr[4];
    #pragma unroll
    for (int i = 0; i < 4; i++) af[i] = *(const bf16x8*)&As[cur][(wm * 64 + i * 16 + lm) * 32 + quad * 8];
    #pragma unroll
    for (int j = 0; j < 4; j++) bfr[j] = *(const bf16x8*)&Bs[cur][(wn * 64 + j * 16 + lm) * 32 + quad * 8];
    lgkm0();
    #pragma unroll
    for (int i = 0; i < 4; i++)
      #pragma unroll
      for (int j = 0; j < 4; j++)
        acc[i][j] = __builtin_amdgcn_mfma_f32_16x16x32_bf16(af[i], bfr[j], acc[i][j], 0, 0, 0);
    barx();
  }
  #pragma unroll
  for (int i = 0; i < 4; i++) {
    const int row0 = m0 + wm * 64 + i * 16 + quad * 4;
    #pragma unroll
    for (int j = 0; j < 4; j++) {
      const int col = n0 + wn * 64 + j * 16 + lm;
      const float bv = bias[col];
      #pragma unroll
      for (int r = 0; r < 4; r++) {
        const size_t idx = (size_t)(row0 + r) * DD + col;
        outp[idx] = acc[i][j][r] + bv + resid[idx];
      }
    }
  }
}

// ---------------- fp8 PV GEMM: 256 thr, 128x128 tiles, BK=64, counted-vmcnt dbuf ----------------
// contraction dim (tokens) interleaved via fperm on both P8 and vT8
// MODE 3: bf16 out scaled by 1/lsum[row]; MODE 4: fp32 partial, K-range by blockIdx.z
template <int MODE>
__launch_bounds__(256, 3)
__global__ void gemm_fp8_kernel(const u8* __restrict__ A, const u8* __restrict__ BT,
                                int K, int lda, int ldb, void* __restrict__ outp,
                                const float* __restrict__ lsum) {
  __shared__ __align__(16) u8 As[2][128 * 64];
  __shared__ __align__(16) u8 Bs[2][128 * 64];
  const int m0 = blockIdx.x * 128, n0 = blockIdx.y * 128;
  const int tid = threadIdx.x;
  const int w = tid >> 6, lane = tid & 63, lm = lane & 15, quad = lane >> 4;
  const int wm = w & 1, wn = w >> 1;
  f32x4 acc[4][4] = {};
  const int srow = tid >> 2;                                    // 0..63
  const int scol = ((tid & 3) ^ ((srow >> 1) & 3)) * 16;        // swizzled global chunk
  const size_t kbase = (MODE == 4) ? (size_t)blockIdx.z * (size_t)K : 0;
  const u8* Ag = A + (size_t)(m0 + srow) * lda + kbase + scol;
  const u8* Bg = BT + (size_t)(n0 + srow) * ldb + kbase + scol;
  u8* Al = (u8*)As + w * 1024;
  u8* Bl = (u8*)Bs + w * 1024;
  const size_t ars = (size_t)64 * lda;
  const size_t brs = (size_t)64 * ldb;
  const int csel = ((quad ^ ((lm >> 1) & 3)) * 16);

  auto stage = [&](int kk, int buf) {
    const u8* ag = Ag + kk;
    const u8* bg = Bg + kk;
    u8* al = Al + buf * 8192;
    u8* bl = Bl + buf * 8192;
    gload16(ag, al);
    gload16(ag + ars, al + 4096);
    gload16(bg, bl);
    gload16(bg + brs, bl + 4096);
  };

  stage(0, 0);
  int cur = 0;
  for (int kk = 0; kk < K; kk += 64) {
    if (kk + 64 < K) { stage(kk + 64, cur ^ 1); vm4bar(); }
    else vm0bar();
    i64x2 afv[4], bfv[4];
    #pragma unroll
    for (int i = 0; i < 4; i++)
      afv[i] = *(const i64x2*)&As[cur][(wm * 64 + i * 16 + lm) * 64 + csel];
    #pragma unroll
    for (int j = 0; j < 4; j++)
      bfv[j] = *(const i64x2*)&Bs[cur][(wn * 64 + j * 16 + lm) * 64 + csel];
    lgkm0();
    #pragma unroll
    for (int i = 0; i < 4; i++)
      #pragma unroll
      for (int j = 0; j < 4; j++) {
        acc[i][j] = __builtin_amdgcn_mfma_f32_16x16x32_fp8_fp8(afv[i].x, bfv[j].x, acc[i][j], 0, 0, 0);
        acc[i][j] = __builtin_amdgcn_mfma_f32_16x16x32_fp8_fp8(afv[i].y, bfv[j].y, acc[i][j], 0, 0, 0);
      }
    barx();
    cur ^= 1;
  }
  #pragma unroll
  for (int i = 0; i < 4; i++) {
    const int row0 = m0 + wm * 64 + i * 16 + quad * 4;
    float li[4];
    if (MODE == 3) {
      #pragma unroll
      for (int r = 0; r < 4; r++) li[r] = 1.0f / lsum[row0 + r];
    }
    #pragma unroll
    for (int j = 0; j < 4; j++) {
      const int col = n0 + wn * 64 + j * 16 + lm;
      if (MODE == 3) {
        #pragma unroll
        for (int r = 0; r < 4; r++)
          ((u16*)outp)[(size_t)(row0 + r) * DD + col] = f2bf(acc[i][j][r] * li[r]);
      } else {
        float* po = (float*)outp + (size_t)blockIdx.z * NTOK * DD;
        #pragma unroll
        for (int r = 0; r < 4; r++)
          po[(size_t)(row0 + r) * DD + col] = acc[i][j][r];
      }
    }
  }
}

// ---------------- split-K PV reduce (4 parts): attnb = (sum parts) / lsum ----------------
__global__ void pv_reduce_kernel(const float* __restrict__ part, const float* __restrict__ lsum,
                                 u16* __restrict__ attnb) {
  const int idx = blockIdx.x * 256 + threadIdx.x;
  const int row = idx >> 7;
  const int c4 = (idx & 127) << 2;
  const float* p = part + (size_t)row * DD + c4;
  const size_t stride = (size_t)NTOK * DD;
  float4 a = *(const float4*)(p);
  float4 b = *(const float4*)(p + stride);
  float4 c = *(const float4*)(p + 2 * stride);
  float4 d = *(const float4*)(p + 3 * stride);
  const float inv = 1.0f / lsum[row];
  ushort4 o;
  o.x = f2bf((a.x + b.x + c.x + d.x) * inv);
  o.y = f2bf((a.y + b.y + c.y + d.y) * inv);
  o.z = f2bf((a.z + b.z + c.z + d.z) * inv);
  o.w = f2bf((a.w + b.w + c.w + d.w) * inv);
  *(ushort4*)(attnb + (size_t)row * DD + c4) = o;
}

// ---------------- scores: fp8 QK^T, 64 q-rows x 512-key chunk, 512 thr, BK=64 ----------------
// R2/R5 arrangement (best measured: 87 µs): rotated single-barrier pipeline —
// stage(t+1) at top, vmcnt(0)+barrier at bottom; issue->wait window = one full
// compute phase, one barrier/iter.
__launch_bounds__(512, 4)
__global__ void scores_kernel(const u8* __restrict__ qb8, const u8* __restrict__ kb8,
                              u8* __restrict__ P8, float* __restrict__ lsum) {
  __shared__ __align__(16) u8 As[2][64 * 64];    // 2 x 4 KB
  __shared__ __align__(16) u8 Bs[2][512 * 64];   // 2 x 32 KB
  __shared__ float hS[8][64], hP[8][64], hZ[64];
  const int m0 = blockIdx.x * 64;
  const int c = blockIdx.y;
  const int tid = threadIdx.x;
  const int w = tid >> 6, lane = tid & 63, lm = lane & 15, quad = lane >> 4;
  const int wsl = w;                          // key slice 0..7 (64 keys each)
  f32x4 s[4][4] = {};
  const int srA = tid >> 2;                                   // A: 0..63 ; B: 0..127
  const int scS = ((tid & 3) ^ ((srA >> 1) & 3)) * 16;        // staging swizzle
  const u8* Qg = qb8 + (size_t)(m0 + srA) * DD + scS;         // deref'd only for tid<256
  const u8* Kg = kb8 + (size_t)(c * CHK + srA) * DD + scS;
  u8* Al = (u8*)As + w * 1024;                // waves 0..3 stage A (4 KB)
  u8* Bl = (u8*)Bs + w * 1024;                // all 8 waves stage B (4 x 8 KB slabs)
  const int csel = ((quad ^ ((lm >> 1) & 3)) * 16);

  auto stage = [&](int kk, int buf) {
    u8* al = Al + buf * 4096;
    u8* bl = Bl + buf * 32768;
    if (tid < 256) gload16(Qg + kk, al);
    gload16(Kg + kk, bl);
    gload16(Kg + kk + (size_t)128 * DD, bl + 8192);
    gload16(Kg + kk + (size_t)256 * DD, bl + 16384);
    gload16(Kg + kk + (size_t)384 * DD, bl + 24576);
  };

  stage(0, 0);
  vm0bar();
  #pragma unroll
  for (int t = 0; t < 8; ++t) {
    const int cur = t & 1;
    if (t < 7) stage((t + 1) * 64, cur ^ 1);
    i64x2 afv[4], bfv[4];
    #pragma unroll
    for (int i = 0; i < 4; i++)
      afv[i] = *(const i64x2*)&As[cur][(i * 16 + lm) * 64 + csel];
    #pragma unroll
    for (int j = 0; j < 4; j++)
      bfv[j] = *(const i64x2*)&Bs[cur][(wsl * 64 + j * 16 + lm) * 64 + csel];
    lgkm0();
    __builtin_amdgcn_s_setprio(1);
    #pragma unroll
    for (int i = 0; i < 4; i++)
      #pragma unroll
      for (int j = 0; j < 4; j++) {
        s[i][j] = __builtin_amdgcn_mfma_f32_16x16x32_fp8_fp8(afv[i].x, bfv[j].x, s[i][j], 0, 0, 0);
        s[i][j] = __builtin_amdgcn_mfma_f32_16x16x32_fp8_fp8(afv[i].y, bfv[j].y, s[i][j], 0, 0, 0);
      }
    __builtin_amdgcn_s_setprio(0);
    vm0bar();   // next-tile loads landed while MFMAs ran
  }
  // ---- phase A: e = exp2(s_raw * SCL*LOG2E); per-wave (64-col) partial row sums (DPP) ----
  #pragma unroll
  for (int i = 0; i < 4; i++) {
    #pragma unroll
    for (int reg = 0; reg < 4; reg++) {
      float z = 0.f;
      #pragma unroll
      for (int j = 0; j < 4; j++) {
        float e = exp2f(s[i][j][reg] * SCLL);
        s[i][j][reg] = e;
        z += e;
      }
      z = rowsum16(z);
      if (lm == 0) hS[wsl][i * 16 + quad * 4 + reg] = z;
    }
  }
  __syncthreads();
  // ---- phase B: row totals -> hZ = LOG2E / Z ----
  if (tid < 64) {
    float t = 0.f;
    #pragma unroll
    for (int w2 = 0; w2 < 8; w2++) t += hS[w2][tid];
    hZ[tid] = LOG2E / t;
  }
  __syncthreads();
  // ---- phase C: p = exp2(e * LOG2E/Z); fp8 packed store in fperm layout; partial l ----
  const int newc = ((lm >> 1) & 3) * 2 + (lm >> 3);
  const int pbyte = wsl * 64 + newc * 8 + (lm & 1) * 4;
  #pragma unroll
  for (int i = 0; i < 4; i++) {
    #pragma unroll
    for (int reg = 0; reg < 4; reg++) {
      const int rl = i * 16 + quad * 4 + reg;
      const float iz = hZ[rl];
      const float p0 = exp2f(s[i][0][reg] * iz);
      const float p1 = exp2f(s[i][1][reg] * iz);
      const float p2 = exp2f(s[i][2][reg] * iz);
      const float p3 = exp2f(s[i][3][reg] * iz);
      float zp = (p0 + p1) + (p2 + p3);
      zp = rowsum16(zp);
      if (lm == 0) hP[wsl][rl] = zp;
      uint32_t o = __builtin_amdgcn_cvt_pk_fp8_f32(p0, p1, 0, false);
      o = __builtin_amdgcn_cvt_pk_fp8_f32(p2, p3, o, true);
      *(uint32_t*)(P8 + (size_t)(m0 + rl) * NTOK + c * CHK + pbyte) = o;
    }
  }
  __syncthreads();
  if (tid < 64) {
    float t = 0.f;
    #pragma unroll
    for (int w2 = 0; w2 < 8; w2++) t += hP[w2][tid];
    atomicAdd(&lsum[m0 + tid], t);
  }
}

// ---------------- cls row (exact fp32) ----------------
__global__ void cls_u_kernel(const float* __restrict__ Wk, const float* __restrict__ bk,
                             const float* __restrict__ q0g, float* __restrict__ uc) {
  __shared__ float q0[512];
  const int tid = threadIdx.x;
  q0[tid] = q0g[tid];
  q0[tid + 256] = q0g[tid + 256];
  __syncthreads();
  if (blockIdx.x < 8) {
    const int c = blockIdx.x * 64 + (tid >> 2), ii = tid & 3;
    float acc = 0.f;
    #pragma unroll 8
    for (int j = ii; j < 512; j += 4) acc += Wk[(size_t)c * 512 + j] * q0[j];
    acc += __shfl_xor(acc, 1, 64);
    acc += __shfl_xor(acc, 2, 64);
    if (ii == 0) uc[c] = acc;
  } else if (tid < 64) {
    float acc = 0.f;
    #pragma unroll 8
    for (int j = tid; j < 512; j += 64) acc += bk[j] * q0[j];
    #pragma unroll
    for (int off = 1; off < 64; off <<= 1) acc += __shfl_xor(acc, off, 64);
    if (tid == 0) uc[512] = acc;
  }
}

__global__ void cls_scores_kernel(const float* __restrict__ x, const float* __restrict__ uc,
                                  float* __restrict__ s0) {
  __shared__ float u[512];
  __shared__ float c0s;
  int tid = threadIdx.x;  // 256
  for (int i = tid; i < 512; i += 256) u[i] = uc[i];
  if (tid == 0) c0s = uc[512];
  __syncthreads();
  int rowg = blockIdx.x * 32 + (tid >> 3);
  int ii = tid & 7;
  const float* xr = x + rowg * 512;
  float acc = 0.f;
  for (int i = ii; i < 512; i += 8) acc += xr[i] * u[i];
  acc += __shfl_xor(acc, 1, 64);
  acc += __shfl_xor(acc, 2, 64);
  acc += __shfl_xor(acc, 4, 64);
  if (ii == 0) s0[rowg] = (acc + c0s) * SCL;
}

__global__ void cls_softmax_kernel(const float* __restrict__ s0, float* __restrict__ out) {
  int tid = threadIdx.x;  // 1024 = 16 waves, wave w = chunk w
  int w = tid >> 6, lane = tid & 63;
  const float* sc = s0 + w * 512;
  float v[8];
  float m = -1e30f;
  #pragma unroll
  for (int j = 0; j < 8; j++) { v[j] = sc[lane * 8 + j]; m = fmaxf(m, v[j]); }
  for (int off = 1; off < 64; off <<= 1) m = fmaxf(m, __shfl_xor(m, off, 64));
  float z = 0.f;
  #pragma unroll
  for (int j = 0; j < 8; j++) { v[j] = expf(v[j] - m); z += v[j]; }
  for (int off = 1; off < 64; off <<= 1) z += __shfl_xor(z, off, 64);
  float invz = 1.f / z;
  float l = 0.f;
  #pragma unroll
  for (int j = 0; j < 8; j++) { v[j] = expf(v[j] * invz); l += v[j]; }
  for (int off = 1; off < 64; off <<= 1) l += __shfl_xor(l, off, 64);
  __shared__ float lw[16];
  if (lane == 0) lw[w] = l;
  __syncthreads();
  float L = 0.f;
  for (int i = 0; i < 16; i++) L += lw[i];
  float invL = 1.f / L;
  #pragma unroll
  for (int j = 0; j < 8; j++) out[w * 512 + lane * 8 + j] = v[j] * invL;
}

extern "C" void kernel_launch(void* const* d_in, const int* in_sizes, int n_in,
                              void* d_out, int out_size, void* d_ws, size_t ws_size,
                              hipStream_t stream) {
  const float* x  = (const float*)d_in[0];
  const float* Wq = (const float*)d_in[1];
  const float* bq = (const float*)d_in[2];
  const float* Wk = (const float*)d_in[3];
  const float* bk = (const float*)d_in[4];
  const float* Wv = (const float*)d_in[5];
  const float* bv = (const float*)d_in[6];
  const float* Wo = (const float*)d_in[7];
  const float* bo = (const float*)d_in[8];
  float* out = (float*)d_out;

  char* ws = (char*)d_ws;
  u16* xb    = (u16*)(ws);                  // 8 MB
  u16* Wall  = (u16*)(ws + 8388608);        // 1.5 MB
  u16* WoT   = (u16*)(ws + 9961472);        // 512 KB
  u8*  qb8   = (u8*)(ws + 10485760);        // 4 MB fp8 (k-interleaved)
  u8*  kb8   = (u8*)(ws + 14680064);        // 4 MB fp8 (k-interleaved)
  u8*  vT8   = (u8*)(ws + 18874368);        // 4 MB fp8 (fperm tokens)
  u16* attnb = (u16*)(ws + 23068672);       // 8 MB
  float* q0g = (float*)(ws + 31457280);     // 512 f
  float* uc  = (float*)(ws + 31461376);     // 513 f
  float* s0  = (float*)(ws + 31465472);     // 8192 f
  float* lsum= (float*)(ws + 31498240);     // 8192 f
  u8*  P8    = (u8*)(ws + 31531008);        // 64 MB fp8 (fperm token cols)
  float* part= (float*)(ws + 98639872);     // 4 x 16 MB
  const size_t need_full = 98639872ULL + (size_t)KSPLIT * NTOK * DD * 4ULL;

  prep_kernel<<<5122, 256, 0, stream>>>(x, Wq, Wk, Wv, Wo, bq, xb, Wall, WoT, lsum, q0g);

  qkv_kernel<<<dim3(NTOK / 128, 12), 256, 0, stream>>>(xb, Wall, bq, bk, bv, qb8, kb8, vT8);

  scores_kernel<<<dim3(NTOK / 64, NCH), 512, 0, stream>>>(qb8, kb8, P8, lsum);

  if (ws_size >= need_full) {
    gemm_fp8_kernel<4><<<dim3(NTOK / 128, DD / 128, KSPLIT), 256, 0, stream>>>(
        P8, vT8, KLEN, NTOK, NTOK, part, nullptr);
    pv_reduce_kernel<<<NTOK * DD / 4 / 256, 256, 0, stream>>>(part, lsum, attnb);
  } else {
    gemm_fp8_kernel<3><<<dim3(NTOK / 128, DD / 128), 256, 0, stream>>>(
        P8, vT8, NTOK, NTOK, NTOK, attnb, lsum);
  }

  outproj_kernel<<<dim3(NTOK / 128, DD / 128), 256, 0, stream>>>(attnb, WoT, bo, out, x);

  cls_u_kernel<<<9, 256, 0, stream>>>(Wk, bk, q0g, uc);
  cls_scores_kernel<<<NTOK / 32, 256, 0, stream>>>(x, uc, s0);
  cls_softmax_kernel<<<1, 1024, 0, stream>>>(s0, out + (size_t)NTOK * DD);
}